// Round 1
// baseline (246.619 us; speedup 1.0000x reference)
//
#include <hip/hip_runtime.h>

#define NCLS 21
#define BLK 256

__global__ __launch_bounds__(BLK) void focal_main(
    const float* __restrict__ loc_p,
    const float* __restrict__ loc_t,
    const float* __restrict__ cls_p,
    const int*   __restrict__ cls_t,
    float* __restrict__ ws,
    int n_anchors)
{
    __shared__ float lds[BLK * NCLS];          // 21504 B
    __shared__ float red[8];

    const int tid = threadIdx.x;
    const long long anchor0 = (long long)blockIdx.x * BLK;

    // ---- stage 256 anchors x 21 classes into LDS, coalesced float4 ----
    // base offset = blockIdx.x * 21504 bytes -> 16B aligned
    const float4* __restrict__ src = (const float4*)(cls_p + anchor0 * NCLS);
    float4* dst = (float4*)lds;
    const int nvec = BLK * NCLS / 4;           // 1344
    // how many float4s are actually in-bounds for (possibly partial) last block
    long long rem_anchors = (long long)n_anchors - anchor0;
    int valid_vec = nvec;
    if (rem_anchors < BLK) {
        long long vf = rem_anchors > 0 ? rem_anchors * NCLS / 4 : 0;
        valid_vec = (int)vf;
    }
    for (int i = tid; i < valid_vec; i += BLK) dst[i] = src[i];

    const long long a = anchor0 + tid;
    float acc  = 0.0f;
    float npos = 0.0f;

    int t = -1;
    if (a < n_anchors) t = cls_t[a];

    // ---- smooth L1 over positive anchors (float4, coalesced) ----
    if (t > 0) {
        npos = 1.0f;
        float4 lp = ((const float4*)loc_p)[a];
        float4 lt = ((const float4*)loc_t)[a];
        float d0 = lp.x - lt.x, d1 = lp.y - lt.y, d2 = lp.z - lt.z, d3 = lp.w - lt.w;
        float a0 = fabsf(d0), a1 = fabsf(d1), a2 = fabsf(d2), a3 = fabsf(d3);
        acc += (a0 < 1.0f) ? 0.5f * d0 * d0 : a0 - 0.5f;
        acc += (a1 < 1.0f) ? 0.5f * d1 * d1 : a1 - 0.5f;
        acc += (a2 < 1.0f) ? 0.5f * d2 * d2 : a2 - 0.5f;
        acc += (a3 < 1.0f) ? 0.5f * d3 * d3 : a3 - 0.5f;
    }

    __syncthreads();   // staging complete

    // ---- focal loss over non-ignored anchors (t >= 0) ----
    if (t >= 0) {
        const float* row = lds + tid * NCLS;   // stride 21: conflict-free (2-way max)
        float m = row[0];
        #pragma unroll
        for (int j = 1; j < NCLS; ++j) m = fmaxf(m, row[j]);
        float s = 0.0f;
        #pragma unroll
        for (int j = 0; j < NCLS; ++j) s += __expf(row[j] - m);
        float pt = __expf(row[t] - m) / s;
        pt = fminf(fmaxf(pt, 1e-7f), 1.0f - 1e-7f);
        float om = 1.0f - pt;
        acc += -__logf(pt) * om * om;
    }

    // ---- reduction: wave(64) shuffle -> LDS -> 2 atomics per block ----
    #pragma unroll
    for (int off = 32; off > 0; off >>= 1) {
        acc  += __shfl_down(acc,  off, 64);
        npos += __shfl_down(npos, off, 64);
    }
    const int wave = tid >> 6, lane = tid & 63;
    if (lane == 0) { red[wave * 2] = acc; red[wave * 2 + 1] = npos; }
    __syncthreads();
    if (tid == 0) {
        float L = red[0] + red[2] + red[4] + red[6];
        float P = red[1] + red[3] + red[5] + red[7];
        atomicAdd(ws,     L);
        atomicAdd(ws + 1, P);
    }
}

__global__ void focal_final(const float* __restrict__ ws, float* __restrict__ out)
{
    out[0] = ws[0] / ws[1];
}

extern "C" void kernel_launch(void* const* d_in, const int* in_sizes, int n_in,
                              void* d_out, int out_size, void* d_ws, size_t ws_size,
                              hipStream_t stream)
{
    const float* loc_p = (const float*)d_in[0];
    const float* loc_t = (const float*)d_in[1];
    const float* cls_p = (const float*)d_in[2];
    const int*   cls_t = (const int*)d_in[3];
    // d_in[4] (pos) is ignored: pos == (cls_targets > 0) exactly.
    float* out = (float*)d_out;
    float* ws  = (float*)d_ws;

    const int n_anchors = in_sizes[3];                 // B*A = 1,048,576

    hipMemsetAsync(ws, 0, 2 * sizeof(float), stream);  // loss_sum, num_pos

    const int blocks = (n_anchors + BLK - 1) / BLK;    // 4096
    focal_main<<<blocks, BLK, 0, stream>>>(loc_p, loc_t, cls_p, cls_t, ws, n_anchors);
    focal_final<<<1, 1, 0, stream>>>(ws, out);
}

// Round 2
// 169.165 us; speedup vs baseline: 1.4579x; 1.4579x over previous
//
#include <hip/hip_runtime.h>

#define NCLS 21
#define BLK 256
#define CHUNK 256                      // anchors per block
#define STAGE_BYTES (CHUNK * NCLS * 4) // 21504 B, 16B-aligned per block

// async global->LDS, 16B per lane. LDS dest must be the wave-uniform base;
// HW places lane i at base + i*16.
__device__ __forceinline__ void load_lds16(const void* g, void* l) {
    __builtin_amdgcn_global_load_lds(
        (const __attribute__((address_space(1))) unsigned int*)g,
        (__attribute__((address_space(3))) unsigned int*)l,
        16, 0, 0);
}

__global__ __launch_bounds__(BLK) void focal_main(
    const float* __restrict__ loc_p,
    const float* __restrict__ loc_t,
    const float* __restrict__ cls_p,
    const int*   __restrict__ cls_t,
    float2* __restrict__ partials,
    int n_anchors)
{
    __shared__ float lds[CHUNK * NCLS]; // 21504 B -> 7 blocks/CU by LDS
    __shared__ float red[8];

    const int tid  = threadIdx.x;
    const int wave = tid >> 6;
    const int lane = tid & 63;
    const long long anchor0 = (long long)blockIdx.x * CHUNK;
    const long long a = anchor0 + tid;

    // ---- stage 256 anchors x 21 classes via async DMA (21 x 1024B issues) ----
    if (anchor0 + CHUNK <= n_anchors) {
        const char* gbase = (const char*)(cls_p + anchor0 * NCLS);
        char* lbase = (char*)lds;
        #pragma unroll
        for (int k = wave; k < NCLS; k += 4) {  // wave-uniform base per issue
            load_lds16(gbase + k * 1024 + lane * 16, lbase + k * 1024);
        }
    } else {
        // generic tail path (not taken for B*A = 1,048,576)
        long long rem = n_anchors - anchor0;
        int valid = rem > 0 ? (int)(rem * NCLS) : 0;
        for (int i = tid; i < valid; i += BLK)
            lds[i] = cls_p[anchor0 * NCLS + i];
    }

    // ---- overlap per-thread loads with the DMA ----
    int t = -1;
    float4 lp = make_float4(0.f, 0.f, 0.f, 0.f);
    float4 lt = make_float4(0.f, 0.f, 0.f, 0.f);
    if (a < n_anchors) {
        t  = cls_t[a];
        lp = ((const float4*)loc_p)[a];   // unconditional: 91% anchors positive
        lt = ((const float4*)loc_t)[a];
    }

    // ---- smooth L1, masked by (t > 0) ----
    float acc  = 0.0f;
    float npos = 0.0f;
    {
        float d0 = lp.x - lt.x, d1 = lp.y - lt.y, d2 = lp.z - lt.z, d3 = lp.w - lt.w;
        float a0 = fabsf(d0), a1 = fabsf(d1), a2 = fabsf(d2), a3 = fabsf(d3);
        float s = 0.0f;
        s += (a0 < 1.0f) ? 0.5f * d0 * d0 : a0 - 0.5f;
        s += (a1 < 1.0f) ? 0.5f * d1 * d1 : a1 - 0.5f;
        s += (a2 < 1.0f) ? 0.5f * d2 * d2 : a2 - 0.5f;
        s += (a3 < 1.0f) ? 0.5f * d3 * d3 : a3 - 0.5f;
        if (t > 0) { acc = s; npos = 1.0f; }
    }

    __syncthreads();   // drains the global_load_lds DMA + joins staging

    // ---- focal loss over non-ignored anchors (t >= 0) ----
    if (t >= 0) {
        const float* row = lds + tid * NCLS; // stride 21: <=2-way bank alias, free
        float m = row[0];
        #pragma unroll
        for (int j = 1; j < NCLS; ++j) m = fmaxf(m, row[j]);
        float s = 0.0f;
        #pragma unroll
        for (int j = 0; j < NCLS; ++j) s += __expf(row[j] - m);
        float pt = __expf(row[t] - m) / s;
        pt = fminf(fmaxf(pt, 1e-7f), 1.0f - 1e-7f);
        float om = 1.0f - pt;
        acc += -__logf(pt) * om * om;
    }

    // ---- block reduction: wave shuffle -> LDS -> one float2 store (no atomics) ----
    #pragma unroll
    for (int off = 32; off > 0; off >>= 1) {
        acc  += __shfl_down(acc,  off, 64);
        npos += __shfl_down(npos, off, 64);
    }
    if (lane == 0) { red[wave * 2] = acc; red[wave * 2 + 1] = npos; }
    __syncthreads();
    if (tid == 0) {
        float L = red[0] + red[2] + red[4] + red[6];
        float P = red[1] + red[3] + red[5] + red[7];
        partials[blockIdx.x] = make_float2(L, P);
    }
}

__global__ __launch_bounds__(BLK) void focal_reduce(
    const float2* __restrict__ partials, float* __restrict__ out, int npart)
{
    __shared__ float red[8];
    float L = 0.0f, P = 0.0f;
    for (int i = threadIdx.x; i < npart; i += BLK) {
        float2 v = partials[i];
        L += v.x; P += v.y;
    }
    #pragma unroll
    for (int off = 32; off > 0; off >>= 1) {
        L += __shfl_down(L, off, 64);
        P += __shfl_down(P, off, 64);
    }
    const int wave = threadIdx.x >> 6, lane = threadIdx.x & 63;
    if (lane == 0) { red[wave * 2] = L; red[wave * 2 + 1] = P; }
    __syncthreads();
    if (threadIdx.x == 0) {
        float Ls = red[0] + red[2] + red[4] + red[6];
        float Ps = red[1] + red[3] + red[5] + red[7];
        out[0] = Ls / Ps;
    }
}

extern "C" void kernel_launch(void* const* d_in, const int* in_sizes, int n_in,
                              void* d_out, int out_size, void* d_ws, size_t ws_size,
                              hipStream_t stream)
{
    const float* loc_p = (const float*)d_in[0];
    const float* loc_t = (const float*)d_in[1];
    const float* cls_p = (const float*)d_in[2];
    const int*   cls_t = (const int*)d_in[3];
    // d_in[4] (pos) ignored: pos == (cls_targets > 0) exactly.
    float*  out = (float*)d_out;
    float2* ws  = (float2*)d_ws;

    const int n_anchors = in_sizes[3];                    // B*A = 1,048,576
    const int blocks = (n_anchors + CHUNK - 1) / CHUNK;   // 4096

    focal_main<<<blocks, BLK, 0, stream>>>(loc_p, loc_t, cls_p, cls_t, ws, n_anchors);
    focal_reduce<<<1, BLK, 0, stream>>>(ws, out, blocks);
}

// Round 3
// 168.620 us; speedup vs baseline: 1.4626x; 1.0032x over previous
//
#include <hip/hip_runtime.h>

#define NCLS 21
#define BLK 256
#define CHUNK 256                        // anchors per block
#define WAVE_ANCHORS 64
#define WAVE_BYTES (WAVE_ANCHORS * NCLS * 4)   // 5376 B per wave
// s_waitcnt imm: vmcnt(0), lgkmcnt/expcnt unconstrained (gfx9 encoding)
#define WAITCNT_VM0 0x0F70

// async global->LDS, 16B per lane; lane i lands at ldsbase + i*16 (exec-masked)
__device__ __forceinline__ void load_lds16(const void* g, void* l) {
    __builtin_amdgcn_global_load_lds(
        (const __attribute__((address_space(1))) unsigned int*)g,
        (__attribute__((address_space(3))) unsigned int*)l,
        16, 0, 0);
}

__device__ __forceinline__ float focal_row(const float* __restrict__ row, int t) {
    float m = row[0];
    #pragma unroll
    for (int j = 1; j < NCLS; ++j) m = fmaxf(m, row[j]);
    float s = 0.0f;
    #pragma unroll
    for (int j = 0; j < NCLS; ++j) s += __expf(row[j] - m);
    float pt = __expf(row[t] - m) / s;
    pt = fminf(fmaxf(pt, 1e-7f), 1.0f - 1e-7f);
    float om = 1.0f - pt;
    return -__logf(pt) * om * om;
}

__global__ __launch_bounds__(BLK) void focal_main(
    const float* __restrict__ loc_p,
    const float* __restrict__ loc_t,
    const float* __restrict__ cls_p,
    const int*   __restrict__ cls_t,
    float2* __restrict__ partials,
    int n_anchors)
{
    // +192 floats (768B) defensive pad in case last wave's partial DMA issue
    // ever runs wider than its exec mask
    __shared__ float lds[CHUNK * NCLS + 192];   // 22272 B -> 7 blocks/CU

    const int tid  = threadIdx.x;
    const int wave = tid >> 6;
    const int lane = tid & 63;
    const long long anchor0 = (long long)blockIdx.x * CHUNK;
    const long long a = anchor0 + tid;
    const bool full = (anchor0 + CHUNK <= n_anchors);

    // ---- per-wave private staging: 64 anchors x 21 classes = 5376 B ----
    if (full) {
        const char* gw = (const char*)(cls_p + (anchor0 + (long long)wave * WAVE_ANCHORS) * NCLS);
        char* lw = (char*)lds + wave * WAVE_BYTES;
        #pragma unroll
        for (int k = 0; k < 5; ++k)
            load_lds16(gw + k * 1024 + lane * 16, lw + k * 1024);
        if (lane < 16)
            load_lds16(gw + 5120 + lane * 16, lw + 5120);
    }

    // ---- per-thread loads (issued after DMA; their waits subsume it) ----
    int t = -1;
    float4 lp = make_float4(0.f, 0.f, 0.f, 0.f);
    float4 lt = make_float4(0.f, 0.f, 0.f, 0.f);
    if (a < n_anchors) {
        t  = cls_t[a];
        lp = ((const float4*)loc_p)[a];
        lt = ((const float4*)loc_t)[a];
    }

    // ---- smooth L1, masked by (t > 0) ----
    float acc  = 0.0f;
    float npos = 0.0f;
    {
        float d0 = lp.x - lt.x, d1 = lp.y - lt.y, d2 = lp.z - lt.z, d3 = lp.w - lt.w;
        float a0 = fabsf(d0), a1 = fabsf(d1), a2 = fabsf(d2), a3 = fabsf(d3);
        float s = 0.0f;
        s += (a0 < 1.0f) ? 0.5f * d0 * d0 : a0 - 0.5f;
        s += (a1 < 1.0f) ? 0.5f * d1 * d1 : a1 - 0.5f;
        s += (a2 < 1.0f) ? 0.5f * d2 * d2 : a2 - 0.5f;
        s += (a3 < 1.0f) ? 0.5f * d3 * d3 : a3 - 0.5f;
        if (t > 0) { acc = s; npos = 1.0f; }
    }

    // ---- focal loss; wave reads only LDS it staged itself -> no barrier ----
    if (full) {
        __builtin_amdgcn_s_waitcnt(WAITCNT_VM0);   // drain this wave's DMA
        if (t >= 0)
            acc += focal_row(lds + tid * NCLS, t); // stride-21: <=2-way alias, free
    } else if (t >= 0) {
        acc += focal_row(cls_p + a * NCLS, t);     // rare tail: direct global
    }

    // ---- per-wave reduction, one float2 store per wave, no atomics ----
    #pragma unroll
    for (int off = 32; off > 0; off >>= 1) {
        acc  += __shfl_down(acc,  off, 64);
        npos += __shfl_down(npos, off, 64);
    }
    if (lane == 0)
        partials[blockIdx.x * 4 + wave] = make_float2(acc, npos);
}

#define RBLK 1024
__global__ __launch_bounds__(RBLK) void focal_reduce(
    const float2* __restrict__ partials, float* __restrict__ out, int npart)
{
    __shared__ float red[32];
    float L = 0.0f, P = 0.0f;
    for (int i = threadIdx.x; i < npart; i += RBLK) {
        float2 v = partials[i];
        L += v.x; P += v.y;
    }
    #pragma unroll
    for (int off = 32; off > 0; off >>= 1) {
        L += __shfl_down(L, off, 64);
        P += __shfl_down(P, off, 64);
    }
    const int wave = threadIdx.x >> 6, lane = threadIdx.x & 63;
    if (lane == 0) { red[wave * 2] = L; red[wave * 2 + 1] = P; }
    __syncthreads();
    if (threadIdx.x == 0) {
        float Ls = 0.0f, Ps = 0.0f;
        #pragma unroll
        for (int w = 0; w < RBLK / 64; ++w) { Ls += red[w * 2]; Ps += red[w * 2 + 1]; }
        out[0] = Ls / Ps;
    }
}

extern "C" void kernel_launch(void* const* d_in, const int* in_sizes, int n_in,
                              void* d_out, int out_size, void* d_ws, size_t ws_size,
                              hipStream_t stream)
{
    const float* loc_p = (const float*)d_in[0];
    const float* loc_t = (const float*)d_in[1];
    const float* cls_p = (const float*)d_in[2];
    const int*   cls_t = (const int*)d_in[3];
    // d_in[4] (pos) ignored: pos == (cls_targets > 0) exactly.
    float*  out = (float*)d_out;
    float2* ws  = (float2*)d_ws;

    const int n_anchors = in_sizes[3];                    // B*A = 1,048,576
    const int blocks = (n_anchors + CHUNK - 1) / CHUNK;   // 4096

    focal_main<<<blocks, BLK, 0, stream>>>(loc_p, loc_t, cls_p, cls_t, ws, n_anchors);
    focal_reduce<<<1, RBLK, 0, stream>>>(ws, out, blocks * 4);
}